// Round 14
// baseline (152.993 us; speedup 1.0000x reference)
//
#include <hip/hip_runtime.h>
#include <hip/hip_bf16.h>
#include <stdint.h>

typedef unsigned short u16;
typedef __attribute__((ext_vector_type(8))) short bf16x8;
typedef __attribute__((ext_vector_type(4))) float f32x4;

#define NN 8192
#define HH 256
#define KK 100
#define BB 32
#define LL 128
#define NPAD 1024
#define SPLITK 8
#define KCH (NN / SPLITK)   // 1024
#define STEPS1 (KCH / 64)   // 16
#define STEPS2 (512 / 64)   // 8

__device__ __forceinline__ u16 f2bf_rne(float x) {
  union { __hip_bfloat16 h; u16 u; } v;
  v.h = __float2bfloat16(x);
  return v.u;
}

__device__ __forceinline__ float bf2f(u16 u) {
  union { unsigned int i; float f; } v;
  v.i = ((unsigned int)u) << 16;
  return v.f;
}

__device__ __forceinline__ bf16x8 pack8(f32x4 a, f32x4 b) {
  bf16x8 r;
  r[0] = (short)f2bf_rne(a.x); r[1] = (short)f2bf_rne(a.y);
  r[2] = (short)f2bf_rne(a.z); r[3] = (short)f2bf_rne(a.w);
  r[4] = (short)f2bf_rne(b.x); r[5] = (short)f2bf_rne(b.y);
  r[6] = (short)f2bf_rne(b.z); r[7] = (short)f2bf_rne(b.w);
  return r;
}

// async global->LDS, 16B/lane. LDS dest wave-uniform; HW adds lane*16. Global src per-lane.
__device__ __forceinline__ void gld16(const void* g, void* l) {
  __builtin_amdgcn_global_load_lds(
      (const __attribute__((address_space(1))) unsigned int*)g,
      (__attribute__((address_space(3))) unsigned int*)l, 16, 0, 0);
}

// ---------------------------------------------------------------- embT: [256][8192] bf16 = emb^T
__global__ __launch_bounds__(256) void convert_embT(const float* __restrict__ emb,
                                                    u16* __restrict__ embT) {
  __shared__ float t[64][65];
  const int tid = threadIdx.x;
  const int k0 = blockIdx.x * 64, n0 = blockIdx.y * 64;
#pragma unroll
  for (int i = 0; i < 16; ++i) {
    int idx = i * 256 + tid;
    int r = idx >> 6, c = idx & 63;
    t[r][c] = emb[(size_t)(k0 + r) * HH + n0 + c];
  }
  __syncthreads();
#pragma unroll
  for (int i = 0; i < 16; ++i) {
    int idx = i * 256 + tid;
    int r = idx >> 6, c = idx & 63;
    embT[(size_t)(n0 + r) * NN + k0 + c] = f2bf_rne(t[c][r]);
  }
}

// ---------------------------------------------------------------- dedup: bitmap + scan over 8192 rows
__global__ __launch_bounds__(1024) void dedup_rows(const int* __restrict__ q_idx,
                                                   const int* __restrict__ a_idx,
                                                   int* __restrict__ rank,
                                                   int* __restrict__ rows,
                                                   int* __restrict__ muniq) {
  __shared__ unsigned bm[256];
  __shared__ int cnt[1024];
  __shared__ int total;
  const int tid = threadIdx.x;
  if (tid < 256) bm[tid] = 0u;
  __syncthreads();
  for (int i = tid; i < BB * LL; i += 1024) {
    int q = q_idx[i];
    atomicOr(&bm[q >> 5], 1u << (q & 31));
  }
  for (int i = tid; i < BB * LL; i += 1024) {
    int a = a_idx[i];
    atomicOr(&bm[a >> 5], 1u << (a & 31));
  }
  __syncthreads();
  const unsigned w = bm[tid >> 2];
  const unsigned byte = (w >> ((tid & 3) * 8)) & 0xffu;
  const int myc = __popc(byte);
  cnt[tid] = myc;
  __syncthreads();
  for (int off = 1; off < 1024; off <<= 1) {
    int v = (tid >= off) ? cnt[tid - off] : 0;
    __syncthreads();
    cnt[tid] += v;
    __syncthreads();
  }
  if (tid == 1023) total = cnt[1023];
  int base = cnt[tid] - myc;
#pragma unroll
  for (int j = 0; j < 8; ++j) {
    int n = tid * 8 + j;
    int bit = (byte >> j) & 1;
    rank[n] = base;
    if (bit) rows[base++] = n;
  }
  __syncthreads();
  if (tid == 0) *muniq = total;
  if (tid < 128) rows[total + tid] = 0;
}

// ---------------------------------------------------------------- layer1f: max-streams variant
// BM=64, BN=128, BK=64, 256 thr (4 waves, wave=64x32), 32 KB LDS -> 5 blocks/CU.
// grid 2048: sk=wg&7, nt=(wg>>3)&1, mt=wg>>4. Early-exit on mt.
__global__ __launch_bounds__(256, 5) void gemm_layer1f(const float* __restrict__ adj,
                                                       const u16* __restrict__ embT,
                                                       const int* __restrict__ rows,
                                                       const int* __restrict__ muniq,
                                                       u16* __restrict__ parts) {
  __shared__ __align__(16) float As[64 * 64];  // 16 KB, 16-granule swizzle ^(row&15)
  __shared__ __align__(16) u16 Bs[128 * 64];   // 16 KB, 8-granule swizzle ^(row&7)
  const int tid = threadIdx.x;
  const int lane = tid & 63, wid = tid >> 6;   // 4 waves
  const int wg = blockIdx.x;
  const int sk = wg & 7;
  const int nt = (wg >> 3) & 1;
  const int mt = wg >> 4;
  const int m0 = mt * 64;
  const int M = *muniq;
  if (m0 >= M) return;
  const int n0 = nt * 128;
  const int kbeg = sk * KCH;

  f32x4 acc[4][2];
  const f32x4 zf = {0.f, 0.f, 0.f, 0.f};
#pragma unroll
  for (int i = 0; i < 4; ++i)
#pragma unroll
    for (int j = 0; j < 2; ++j) acc[i][j] = zf;

  // A staging: 16 instrs (4/wave). instr t: rows t*4..+3, 16 granules. row=t*4+(lane>>4), g=lane&15.
  const float* aSrc[4];
#pragma unroll
  for (int j = 0; j < 4; ++j) {
    int t = wid * 4 + j;
    int rloc = t * 4 + (lane >> 4);
    int g = (lane & 15) ^ (rloc & 15);
    int grow = rows[m0 + rloc];
    aSrc[j] = adj + (size_t)grow * NN + kbeg + g * 4;
  }
  // B staging: 16 instrs (4/wave). instr t: rows t*8..+7, 8 granules. row=t*8+(lane>>3), g=lane&7.
  const u16* bSrc[4];
#pragma unroll
  for (int j = 0; j < 4; ++j) {
    int t = wid * 4 + j;
    int rowB = t * 8 + (lane >> 3);
    int g = (lane & 7) ^ (rowB & 7);
    bSrc[j] = embT + (size_t)(n0 + rowB) * NN + kbeg + g * 8;
  }

  for (int s = 0; s < STEPS1; ++s) {
    const int ks = s * 64;
#pragma unroll
    for (int j = 0; j < 4; ++j) {
      gld16(aSrc[j] + ks, (void*)&As[(wid * 4 + j) * 256]);
      gld16(bSrc[j] + ks, (void*)&Bs[(wid * 4 + j) * 512]);
    }
    __syncthreads();
#pragma unroll
    for (int kk = 0; kk < 64; kk += 32) {
      bf16x8 af[4], bfr[2];
      const int g0 = (kk >> 2) + ((lane >> 4) << 1);
#pragma unroll
      for (int mi = 0; mi < 4; ++mi) {
        int row = mi * 16 + (lane & 15);
        f32x4 p0 = *reinterpret_cast<const f32x4*>(&As[row * 64 + ((g0 ^ (row & 15)) << 2)]);
        f32x4 p1 = *reinterpret_cast<const f32x4*>(&As[row * 64 + (((g0 + 1) ^ (row & 15)) << 2)]);
        af[mi] = pack8(p0, p1);
      }
      const int gb = (kk >> 3) + (lane >> 4);
#pragma unroll
      for (int ni = 0; ni < 2; ++ni) {
        int row = wid * 32 + ni * 16 + (lane & 15);
        bfr[ni] = *reinterpret_cast<const bf16x8*>(&Bs[row * 64 + ((gb ^ (row & 7)) << 3)]);
      }
#pragma unroll
      for (int mi = 0; mi < 4; ++mi)
#pragma unroll
        for (int ni = 0; ni < 2; ++ni)
          acc[mi][ni] = __builtin_amdgcn_mfma_f32_16x16x32_bf16(af[mi], bfr[ni], acc[mi][ni], 0, 0, 0);
    }
    __syncthreads();
  }

  u16* outp = parts + (size_t)sk * ((size_t)NN * HH);
  const int r0 = (lane >> 4) << 2;
  const int coln = n0 + wid * 32 + (lane & 15);
#pragma unroll
  for (int mi = 0; mi < 4; ++mi)
#pragma unroll
    for (int ni = 0; ni < 2; ++ni)
#pragma unroll
      for (int r = 0; r < 4; ++r)
        outp[(size_t)(m0 + mi * 16 + r0 + r) * HH + coln + ni * 16] = f2bf_rne(acc[mi][ni][r]);
}

// ---------------------------------------------------------------- gather: bf16 Q/A rows = sum of bf16 split-K parts
__global__ __launch_bounds__(256) void gather_qa(const u16* __restrict__ parts,
                                                 const int* __restrict__ q_idx,
                                                 const int* __restrict__ a_idx,
                                                 const int* __restrict__ rank,
                                                 u16* __restrict__ Qbf, u16* __restrict__ Abf) {
  const int rb = blockIdx.x;
  const bool isA = rb >= BB * LL;
  const int r = isA ? rb - BB * LL : rb;
  const int idx = (isA ? a_idx : q_idx)[r];
  const int cidx = rank[idx];
  const int tid = threadIdx.x;
  float s = 0.f;
#pragma unroll
  for (int p = 0; p < SPLITK; ++p)
    s += bf2f(parts[(size_t)p * ((size_t)NN * HH) + (size_t)cidx * HH + tid]);
  (isA ? Abf : Qbf)[(size_t)r * HH + tid] = f2bf_rne(s);
}

// ---------------------------------------------------------------- fused attention: score MFMA + row/col softmax
__global__ __launch_bounds__(512) void attn_fused(const u16* __restrict__ Qbf,
                                                  const u16* __restrict__ Abf,
                                                  u16* __restrict__ wqbf,
                                                  u16* __restrict__ watbf) {
  __shared__ __align__(16) char lraw[131072];
  u16* Qs = (u16*)lraw;
  u16* As = (u16*)(lraw + 65536);
  float* sc = (float*)lraw;
  const int b = blockIdx.x;
  const int tid = threadIdx.x;
  const int lane = tid & 63, wid = tid >> 6;
  const int wm = wid >> 2, wn = wid & 3;

  const u16* qsrc = Qbf + (size_t)b * (LL * HH);
  const u16* asrc = Abf + (size_t)b * (LL * HH);
#pragma unroll
  for (int i = 0; i < 8; ++i) {
    int gf = i * 512 + tid;
    int l = gf >> 5, g = gf & 31;
    int gp = g ^ (l & 7);
    *reinterpret_cast<bf16x8*>(&Qs[l * 256 + gp * 8]) = *reinterpret_cast<const bf16x8*>(qsrc + l * 256 + g * 8);
    *reinterpret_cast<bf16x8*>(&As[l * 256 + gp * 8]) = *reinterpret_cast<const bf16x8*>(asrc + l * 256 + g * 8);
  }
  __syncthreads();

  f32x4 acc[4][2];
  const f32x4 zf = {0.f, 0.f, 0.f, 0.f};
#pragma unroll
  for (int i = 0; i < 4; ++i)
#pragma unroll
    for (int j = 0; j < 2; ++j) acc[i][j] = zf;

#pragma unroll
  for (int ks = 0; ks < 8; ++ks) {
    bf16x8 af[4], bfr[2];
#pragma unroll
    for (int mi = 0; mi < 4; ++mi) {
      int row = wm * 64 + mi * 16 + (lane & 15);
      int g = ks * 4 + (lane >> 4);
      af[mi] = *reinterpret_cast<const bf16x8*>(&Qs[row * 256 + (g ^ (row & 7)) * 8]);
    }
#pragma unroll
    for (int ni = 0; ni < 2; ++ni) {
      int row = wn * 32 + ni * 16 + (lane & 15);
      int g = ks * 4 + (lane >> 4);
      bfr[ni] = *reinterpret_cast<const bf16x8*>(&As[row * 256 + (g ^ (row & 7)) * 8]);
    }
#pragma unroll
    for (int mi = 0; mi < 4; ++mi)
#pragma unroll
      for (int ni = 0; ni < 2; ++ni)
        acc[mi][ni] = __builtin_amdgcn_mfma_f32_16x16x32_bf16(af[mi], bfr[ni], acc[mi][ni], 0, 0, 0);
  }
  __syncthreads();

  const int r0 = (lane >> 4) << 2;
#pragma unroll
  for (int mi = 0; mi < 4; ++mi)
#pragma unroll
    for (int ni = 0; ni < 2; ++ni) {
      int m = wn * 32 + ni * 16 + (lane & 15);
#pragma unroll
      for (int r = 0; r < 4; ++r) {
        int l = wm * 64 + mi * 16 + r0 + r;
        sc[l * 132 + m] = acc[mi][ni][r];
      }
    }
  __syncthreads();

  {
    const int l = tid >> 2, j = tid & 3;
    const int base = l * 132 + j * 32;
    float mx = -3.4e38f;
#pragma unroll 8
    for (int c = 0; c < 32; ++c) mx = fmaxf(mx, sc[base + c]);
    mx = fmaxf(mx, __shfl_xor(mx, 1));
    mx = fmaxf(mx, __shfl_xor(mx, 2));
    float sum = 0.f;
#pragma unroll 8
    for (int c = 0; c < 32; ++c) sum += expf(sc[base + c] - mx);
    sum += __shfl_xor(sum, 1);
    sum += __shfl_xor(sum, 2);
    float inv = 1.f / sum;
    u16* o = wqbf + (size_t)b * (LL * LL) + l * 128 + j * 32;
#pragma unroll 8
    for (int c = 0; c < 32; ++c) o[c] = f2bf_rne(expf(sc[base + c] - mx) * inv);
  }
  {
    const int m = tid >> 2, j = tid & 3;
    float mx = -3.4e38f;
#pragma unroll 8
    for (int r = 0; r < 32; ++r) mx = fmaxf(mx, sc[(j * 32 + r) * 132 + m]);
    mx = fmaxf(mx, __shfl_xor(mx, 1));
    mx = fmaxf(mx, __shfl_xor(mx, 2));
    float sum = 0.f;
#pragma unroll 8
    for (int r = 0; r < 32; ++r) sum += expf(sc[(j * 32 + r) * 132 + m] - mx);
    sum += __shfl_xor(sum, 1);
    sum += __shfl_xor(sum, 2);
    float inv = 1.f / sum;
    u16* o = watbf + (size_t)b * (LL * LL) + m * 128 + j * 32;
#pragma unroll 8
    for (int r = 0; r < 32; ++r) o[r] = f2bf_rne(expf(sc[(j * 32 + r) * 132 + m] - mx) * inv);
  }
}

// ---------------------------------------------------------------- align via MFMA: E = w @ src; tq/ta -> Tbf
__global__ __launch_bounds__(512) void align_mfma(const u16* __restrict__ wqbf,
                                                  const u16* __restrict__ watbf,
                                                  const u16* __restrict__ Qbf,
                                                  const u16* __restrict__ Abf,
                                                  u16* __restrict__ Tbf) {
  __shared__ __align__(16) u16 wsh[128 * 128];
  __shared__ __align__(16) u16 srcT[256 * 140];
  const int bid = blockIdx.x;
  const int side = bid >> 5, b = bid & 31;
  const int tid = threadIdx.x;
  const int lane = tid & 63, wid = tid >> 6;
  const int wm = wid >> 2, wn = wid & 3;

  const u16* wsrc = (side ? watbf : wqbf) + (size_t)b * (LL * LL);
  const u16* ssrc = (side ? Qbf : Abf) + (size_t)b * (LL * HH);
  const u16* msrc = (side ? Abf : Qbf) + (size_t)b * (LL * HH);

#pragma unroll
  for (int i = 0; i < 4; ++i) {
    int gf = i * 512 + tid;
    int row = gf >> 4, g = gf & 15;
    int gp = g ^ (row & 7);
    *reinterpret_cast<bf16x8*>(&wsh[row * 128 + gp * 8]) = *reinterpret_cast<const bf16x8*>(wsrc + row * 128 + g * 8);
  }
#pragma unroll
  for (int i = 0; i < 8; ++i) {
    int gf = i * 512 + tid;
    int j = gf >> 5, g = gf & 31;
    bf16x8 v = *reinterpret_cast<const bf16x8*>(ssrc + j * 256 + g * 8);
#pragma unroll
    for (int e = 0; e < 8; ++e) srcT[(g * 8 + e) * 140 + j] = (u16)v[e];
  }
  __syncthreads();

  f32x4 acc[4][4];
  const f32x4 zf = {0.f, 0.f, 0.f, 0.f};
#pragma unroll
  for (int i = 0; i < 4; ++i)
#pragma unroll
    for (int j = 0; j < 4; ++j) acc[i][j] = zf;

#pragma unroll
  for (int ks = 0; ks < 4; ++ks) {
    bf16x8 af[4], bfr[4];
#pragma unroll
    for (int mi = 0; mi < 4; ++mi) {
      int row = wm * 64 + mi * 16 + (lane & 15);
      int g = ks * 4 + (lane >> 4);
      af[mi] = *reinterpret_cast<const bf16x8*>(&wsh[row * 128 + (g ^ (row & 7)) * 8]);
    }
#pragma unroll
    for (int ni = 0; ni < 4; ++ni) {
      int h = wn * 64 + ni * 16 + (lane & 15);
      int k = ks * 32 + ((lane >> 4) << 3);
      bfr[ni] = *reinterpret_cast<const bf16x8*>(&srcT[h * 140 + k]);
    }
#pragma unroll
    for (int mi = 0; mi < 4; ++mi)
#pragma unroll
      for (int ni = 0; ni < 4; ++ni)
        acc[mi][ni] = __builtin_amdgcn_mfma_f32_16x16x32_bf16(af[mi], bfr[ni], acc[mi][ni], 0, 0, 0);
  }

  u16* outp = Tbf + (size_t)(side * 4096 + b * 128) * 512;
  const int r0 = (lane >> 4) << 2;
#pragma unroll
  for (int mi = 0; mi < 4; ++mi)
#pragma unroll
    for (int ni = 0; ni < 4; ++ni) {
      int h = wn * 64 + ni * 16 + (lane & 15);
#pragma unroll
      for (int r = 0; r < 4; ++r) {
        int i2 = wm * 64 + mi * 16 + r0 + r;
        float mv = bf2f(msrc[(size_t)i2 * HH + h]);
        float e = acc[mi][ni][r];
        float d = mv - e;
        outp[(size_t)i2 * 512 + h] = f2bf_rne(d * d);
        outp[(size_t)i2 * 512 + 256 + h] = f2bf_rne(mv * e);
      }
    }
}

// ---------------------------------------------------------------- Wcat bf16 [1024][512]
__global__ __launch_bounds__(256) void prep_wcat(const float* __restrict__ w0,
                                                 const float* __restrict__ w1,
                                                 const float* __restrict__ w2,
                                                 const float* __restrict__ w3,
                                                 u16* __restrict__ Wcat) {
  const int kr = blockIdx.x;
  const int tid = threadIdx.x;
  u16* out = Wcat + (size_t)kr * 512;
  if (kr >= KK * 10) {
    out[tid] = 0;
    out[tid + 256] = 0;
    return;
  }
  const int k = kr / 10, s = kr % 10;
  const float* w;
  int r, fs;
  if (s < 1)      { w = w0; r = s;     fs = 1; }
  else if (s < 3) { w = w1; r = s - 1; fs = 2; }
  else if (s < 6) { w = w2; r = s - 3; fs = 3; }
  else            { w = w3; r = s - 6; fs = 4; }
  const float* src = w + ((size_t)k * fs + r) * 522 + 5;
  out[tid] = f2bf_rne(src[tid]);
  out[tid + 256] = f2bf_rne(src[tid + 256]);
}

// ---------------------------------------------------------------- conv GEMM: D[8192][1024] bf16 = Tbf @ Wcat^T
__global__ __launch_bounds__(512, 4) void gemm_conv(const u16* __restrict__ Tbf,
                                                    const u16* __restrict__ Wcat,
                                                    u16* __restrict__ D) {
  __shared__ __align__(16) u16 As[128 * 64];
  __shared__ __align__(16) u16 Bs[256 * 64];
  const int tid = threadIdx.x;
  const int lane = tid & 63, wid = tid >> 6;
  const int wm = wid >> 2, wn = wid & 3;
  const int m0 = blockIdx.x * 128;
  const int n0 = blockIdx.y * 256;

  f32x4 acc[4][4];
  const f32x4 zf = {0.f, 0.f, 0.f, 0.f};
#pragma unroll
  for (int i = 0; i < 4; ++i)
#pragma unroll
    for (int j = 0; j < 4; ++j) acc[i][j] = zf;

  const int browL = (lane >> 3);
  const int bkL = (lane & 7) << 3;

  for (int s = 0; s < STEPS2; ++s) {
    const int ks = s * 64;
#pragma unroll
    for (int j = 0; j < 2; ++j) {
      int rowA = (wid << 4) + (j << 3) + browL;
      int kA = bkL ^ ((rowA & 7) << 3);
      gld16(Tbf + (size_t)(m0 + rowA) * 512 + ks + kA, (void*)&As[(wid * 2 + j) * 512]);
    }
#pragma unroll
    for (int j = 0; j < 4; ++j) {
      int rowB = (wid << 5) + (j << 3) + browL;
      int kB = bkL ^ ((rowB & 7) << 3);
      gld16(Wcat + (size_t)(n0 + rowB) * 512 + ks + kB, (void*)&Bs[(wid * 4 + j) * 512]);
    }
    __syncthreads();
#pragma unroll
    for (int kk = 0; kk < 64; kk += 32) {
      const int krow = kk + ((lane >> 4) << 3);
      bf16x8 af[4], bfr[4];
#pragma unroll
      for (int mi = 0; mi < 4; ++mi) {
        int row = wm * 64 + mi * 16 + (lane & 15);
        af[mi] = *reinterpret_cast<const bf16x8*>(&As[row * 64 + (krow ^ ((row & 7) << 3))]);
      }
#pragma unroll
      for (int ni = 0; ni < 4; ++ni) {
        int row = wn * 64 + ni * 16 + (lane & 15);
        bfr[ni] = *reinterpret_cast<const bf16x8*>(&Bs[row * 64 + (krow ^ ((row & 7) << 3))]);
      }
#pragma unroll
      for (int mi = 0; mi < 4; ++mi)
#pragma unroll
        for (int ni = 0; ni < 4; ++ni)
          acc[mi][ni] = __builtin_amdgcn_mfma_f32_16x16x32_bf16(af[mi], bfr[ni], acc[mi][ni], 0, 0, 0);
    }
    __syncthreads();
  }

  const int r0 = (lane >> 4) << 2;
  const int coln = n0 + wn * 64 + (lane & 15);
#pragma unroll
  for (int mi = 0; mi < 4; ++mi)
#pragma unroll
    for (int ni = 0; ni < 4; ++ni)
#pragma unroll
      for (int r = 0; r < 4; ++r)
        D[(size_t)(m0 + wm * 64 + mi * 16 + r0 + r) * NPAD + coln + ni * 16] = f2bf_rne(acc[mi][ni][r]);
}

// ---------------------------------------------------------------- shift-sum + bias + relu + maxpool -> re[32][800]
__global__ __launch_bounds__(256) void reduce_conv(const u16* __restrict__ D,
                                                   const float* __restrict__ b0,
                                                   const float* __restrict__ b1,
                                                   const float* __restrict__ b2,
                                                   const float* __restrict__ b3,
                                                   float* __restrict__ re) {
  __shared__ float tile[128][101];
  const int pair = blockIdx.y;
  const int sel = pair >> 5, b = pair & 31;
  const int kc = blockIdx.x;
  const int tid = threadIdx.x;
  const int rowbase = sel * (BB * LL) + b * LL;
  const int c0 = kc * 100;
  for (int idx = tid; idx < 12800; idx += 256) {
    int r = idx / 100, c = idx - r * 100;
    tile[r][c] = bf2f(D[(size_t)(rowbase + r) * NPAD + c0 + c]);
  }
  __syncthreads();
  const int wid = tid >> 6, lane = tid & 63;
  const int offt[4] = {0, 1, 3, 6};
  const int fst[4] = {1, 2, 3, 4};
  for (int o = wid; o < 40; o += 4) {
    const int kk = o >> 2, f = o & 3;
    const int fs = fst[f], off = offt[f];
    const int kg = kc * 10 + kk;
    const float bias = (f == 0 ? b0 : f == 1 ? b1 : f == 2 ? b2 : b3)[kg];
    const int col = kk * 10 + off;
    const int outh = 139 - fs;
    float best = 0.f;
    for (int i = lane; i < outh; i += 64) {
      float s = bias;
#pragma unroll 4
      for (int r = 0; r < 4; ++r) {
        if (r < fs) {
          int j = i + r - 5;
          if (j >= 0 && j < LL) s += tile[j][col + r];
        }
      }
      best = fmaxf(best, s);
    }
    best = fmaxf(best, 0.f);
#pragma unroll
    for (int d = 32; d; d >>= 1) best = fmaxf(best, __shfl_xor(best, d));
    if (lane == 0) re[(size_t)b * 800 + sel * 400 + f * 100 + kg] = best;
  }
}

// ---------------------------------------------------------------- dense + log_softmax -> out[32][2]
__global__ __launch_bounds__(64) void dense_logsm(const float* __restrict__ re,
                                                  const float* __restrict__ dw,
                                                  const float* __restrict__ db,
                                                  float* __restrict__ out) {
  const int b = blockIdx.x;
  const int lane = threadIdx.x;
  const float* r = re + (size_t)b * 800;
  float a0 = 0.f, a1 = 0.f;
  for (int j = lane; j < 800; j += 64) {
    float rv = r[j];
    a0 += rv * dw[j * 2];
    a1 += rv * dw[j * 2 + 1];
  }
#pragma unroll
  for (int d = 32; d; d >>= 1) {
    a0 += __shfl_xor(a0, d);
    a1 += __shfl_xor(a1, d);
  }
  if (lane == 0) {
    a0 += db[0];
    a1 += db[1];
    float mx = fmaxf(a0, a1);
    float lse = mx + logf(expf(a0 - mx) + expf(a1 - mx));
    out[b * 2] = a0 - lse;
    out[b * 2 + 1] = a1 - lse;
  }
}

// ---------------------------------------------------------------- workspace layout (bytes)
static const size_t OFF_PARTS = 0;                         // bf16: 8 * 8192*256 u16 = 33.5 MB (region 67MB)
static const size_t OFF_D     = 0;                         // bf16 [8192][1024] = 16.8 MB, alias
static const size_t OFF_QBF   = 67108864;
static const size_t OFF_ABF   = OFF_QBF + 2097152;
static const size_t OFF_WQB   = OFF_ABF + 2097152;
static const size_t OFF_WAB   = OFF_WQB + 1048576;
static const size_t OFF_RE    = OFF_WAB + 1048576;
static const size_t OFF_TBF   = OFF_RE + 102400;
static const size_t OFF_WCAT  = OFF_TBF + 8388608;
static const size_t OFF_EMBT  = OFF_WCAT + 1048576;
static const size_t OFF_RANK  = OFF_EMBT + 4194304;
static const size_t OFF_ROWS  = OFF_RANK + 32768;
static const size_t OFF_MUNIQ = OFF_ROWS + 33280;

extern "C" void kernel_launch(void* const* d_in, const int* in_sizes, int n_in,
                              void* d_out, int out_size, void* d_ws, size_t ws_size,
                              hipStream_t stream) {
  (void)in_sizes; (void)n_in; (void)out_size; (void)ws_size;
  const float* adj  = (const float*)d_in[0];
  const float* emb  = (const float*)d_in[1];
  const int* q_idx  = (const int*)d_in[2];
  const int* a_idx  = (const int*)d_in[3];
  const float* cw0 = (const float*)d_in[4];
  const float* cb0 = (const float*)d_in[5];
  const float* cw1 = (const float*)d_in[6];
  const float* cb1 = (const float*)d_in[7];
  const float* cw2 = (const float*)d_in[8];
  const float* cb2 = (const float*)d_in[9];
  const float* cw3 = (const float*)d_in[10];
  const float* cb3 = (const float*)d_in[11];
  const float* dw = (const float*)d_in[12];
  const float* db = (const float*)d_in[13];
  float* out = (float*)d_out;

  char* ws = (char*)d_ws;
  u16* parts   = (u16*)(ws + OFF_PARTS);
  u16* Dbuf    = (u16*)(ws + OFF_D);
  u16* Qbf     = (u16*)(ws + OFF_QBF);
  u16* Abf     = (u16*)(ws + OFF_ABF);
  u16* wqbf    = (u16*)(ws + OFF_WQB);
  u16* watbf   = (u16*)(ws + OFF_WAB);
  float* re    = (float*)(ws + OFF_RE);
  u16* Tbf     = (u16*)(ws + OFF_TBF);
  u16* Wcat    = (u16*)(ws + OFF_WCAT);
  u16* embT    = (u16*)(ws + OFF_EMBT);
  int* rank    = (int*)(ws + OFF_RANK);
  int* rows    = (int*)(ws + OFF_ROWS);
  int* muniq   = (int*)(ws + OFF_MUNIQ);

  convert_embT<<<dim3(128, 4), 256, 0, stream>>>(emb, embT);
  dedup_rows<<<1, 1024, 0, stream>>>(q_idx, a_idx, rank, rows, muniq);
  prep_wcat<<<1024, 256, 0, stream>>>(cw0, cw1, cw2, cw3, Wcat);
  gemm_layer1f<<<128 * 2 * SPLITK, 256, 0, stream>>>(adj, embT, rows, muniq, parts);
  gather_qa<<<2 * BB * LL, 256, 0, stream>>>(parts, q_idx, a_idx, rank, Qbf, Abf);
  attn_fused<<<BB, 512, 0, stream>>>(Qbf, Abf, wqbf, watbf);
  align_mfma<<<64, 512, 0, stream>>>(wqbf, watbf, Qbf, Abf, Tbf);
  gemm_conv<<<dim3(64, 4), 512, 0, stream>>>(Tbf, Wcat, Dbuf);
  reduce_conv<<<dim3(10, 64), 256, 0, stream>>>(Dbuf, cb0, cb1, cb2, cb3, re);
  dense_logsm<<<BB, 64, 0, stream>>>(re, dw, db, out);
}

// Round 15
// 132.192 us; speedup vs baseline: 1.1574x; 1.1574x over previous
//
#include <hip/hip_runtime.h>
#include <hip/hip_bf16.h>
#include <stdint.h>

typedef unsigned short u16;
typedef __attribute__((ext_vector_type(8))) short bf16x8;
typedef __attribute__((ext_vector_type(4))) float f32x4;

#define NN 8192
#define HH 256
#define KK 100
#define BB 32
#define LL 128
#define SPLITK 8
#define KCH (NN / SPLITK)   // 1024
#define STEPS1 (KCH / 64)   // 16
#define WCATR 1120          // 7 tiles x 160 rows

__device__ __forceinline__ u16 f2bf_rne(float x) {
  union { __hip_bfloat16 h; u16 u; } v;
  v.h = __float2bfloat16(x);
  return v.u;
}

__device__ __forceinline__ float bf2f(u16 u) {
  union { unsigned int i; float f; } v;
  v.i = ((unsigned int)u) << 16;
  return v.f;
}

__device__ __forceinline__ bf16x8 pack8(f32x4 a, f32x4 b) {
  bf16x8 r;
  r[0] = (short)f2bf_rne(a.x); r[1] = (short)f2bf_rne(a.y);
  r[2] = (short)f2bf_rne(a.z); r[3] = (short)f2bf_rne(a.w);
  r[4] = (short)f2bf_rne(b.x); r[5] = (short)f2bf_rne(b.y);
  r[6] = (short)f2bf_rne(b.z); r[7] = (short)f2bf_rne(b.w);
  return r;
}

// async global->LDS, 16B/lane. LDS dest wave-uniform; HW adds lane*16. Global src per-lane.
__device__ __forceinline__ void gld16(const void* g, void* l) {
  __builtin_amdgcn_global_load_lds(
      (const __attribute__((address_space(1))) unsigned int*)g,
      (__attribute__((address_space(3))) unsigned int*)l, 16, 0, 0);
}

// ---------------------------------------------------------------- embT: [256][8192] bf16 = emb^T
__global__ __launch_bounds__(256) void convert_embT(const float* __restrict__ emb,
                                                    u16* __restrict__ embT) {
  __shared__ float t[64][65];
  const int tid = threadIdx.x;
  const int k0 = blockIdx.x * 64, n0 = blockIdx.y * 64;
#pragma unroll
  for (int i = 0; i < 16; ++i) {
    int idx = i * 256 + tid;
    int r = idx >> 6, c = idx & 63;
    t[r][c] = emb[(size_t)(k0 + r) * HH + n0 + c];
  }
  __syncthreads();
#pragma unroll
  for (int i = 0; i < 16; ++i) {
    int idx = i * 256 + tid;
    int r = idx >> 6, c = idx & 63;
    embT[(size_t)(n0 + r) * NN + k0 + c] = f2bf_rne(t[c][r]);
  }
}

// ---------------------------------------------------------------- dedup: bitmap + scan over 8192 rows
__global__ __launch_bounds__(1024) void dedup_rows(const int* __restrict__ q_idx,
                                                   const int* __restrict__ a_idx,
                                                   int* __restrict__ rank,
                                                   int* __restrict__ rows,
                                                   int* __restrict__ muniq) {
  __shared__ unsigned bm[256];
  __shared__ int cnt[1024];
  __shared__ int total;
  const int tid = threadIdx.x;
  if (tid < 256) bm[tid] = 0u;
  __syncthreads();
  for (int i = tid; i < BB * LL; i += 1024) {
    int q = q_idx[i];
    atomicOr(&bm[q >> 5], 1u << (q & 31));
  }
  for (int i = tid; i < BB * LL; i += 1024) {
    int a = a_idx[i];
    atomicOr(&bm[a >> 5], 1u << (a & 31));
  }
  __syncthreads();
  const unsigned w = bm[tid >> 2];
  const unsigned byte = (w >> ((tid & 3) * 8)) & 0xffu;
  const int myc = __popc(byte);
  cnt[tid] = myc;
  __syncthreads();
  for (int off = 1; off < 1024; off <<= 1) {
    int v = (tid >= off) ? cnt[tid - off] : 0;
    __syncthreads();
    cnt[tid] += v;
    __syncthreads();
  }
  if (tid == 1023) total = cnt[1023];
  int base = cnt[tid] - myc;
#pragma unroll
  for (int j = 0; j < 8; ++j) {
    int n = tid * 8 + j;
    int bit = (byte >> j) & 1;
    rank[n] = base;
    if (bit) rows[base++] = n;
  }
  __syncthreads();
  if (tid == 0) *muniq = total;
  if (tid < 128) rows[total + tid] = 0;
}

// ---------------------------------------------------------------- layer1 compact (R13-proven): parts bf16
__global__ __launch_bounds__(512, 6) void gemm_layer1c(const float* __restrict__ adj,
                                                       const u16* __restrict__ embT,
                                                       const int* __restrict__ rows,
                                                       const int* __restrict__ muniq,
                                                       u16* __restrict__ parts) {
  __shared__ __align__(16) float As[64 * 64];  // 16 KB, 16-granule swizzle ^(row&15)
  __shared__ __align__(16) u16 Bs[256 * 64];   // 32 KB, 8-granule swizzle ^(row&7)
  const int tid = threadIdx.x;
  const int lane = tid & 63, wid = tid >> 6;
  const int wm = wid >> 2, wn = wid & 3;
  const int wg = blockIdx.x;
  const int sk = wg & 7;
  const int mt = wg >> 3;
  const int m0 = mt * 64;
  const int M = *muniq;
  if (m0 >= M) return;
  const int kbeg = sk * KCH;

  f32x4 acc[2][4];
  const f32x4 zf = {0.f, 0.f, 0.f, 0.f};
#pragma unroll
  for (int i = 0; i < 2; ++i)
#pragma unroll
    for (int j = 0; j < 4; ++j) acc[i][j] = zf;

  int aRowLoc[2], aGsrc[2];
  const float* aSrc[2];
#pragma unroll
  for (int j = 0; j < 2; ++j) {
    int t = wid * 2 + j;
    aRowLoc[j] = t * 4 + (lane >> 4);
    aGsrc[j] = (lane & 15) ^ (aRowLoc[j] & 15);
    int grow = rows[m0 + aRowLoc[j]];
    aSrc[j] = adj + (size_t)grow * NN + kbeg + aGsrc[j] * 4;
  }
  const u16* bSrc[4];
#pragma unroll
  for (int j = 0; j < 4; ++j) {
    int t = wid * 4 + j;
    int rowB = t * 8 + (lane >> 3);
    int g = (lane & 7) ^ (rowB & 7);
    bSrc[j] = embT + (size_t)rowB * NN + kbeg + g * 8;
  }

  for (int s = 0; s < STEPS1; ++s) {
    const int ks = s * 64;
#pragma unroll
    for (int j = 0; j < 2; ++j)
      gld16(aSrc[j] + ks, (void*)&As[(wid * 2 + j) * 256]);
#pragma unroll
    for (int j = 0; j < 4; ++j)
      gld16(bSrc[j] + ks, (void*)&Bs[(wid * 4 + j) * 512]);
    __syncthreads();
#pragma unroll
    for (int kk = 0; kk < 64; kk += 32) {
      bf16x8 af[2], bfr[4];
      const int g0 = (kk >> 2) + ((lane >> 4) << 1);
#pragma unroll
      for (int mi = 0; mi < 2; ++mi) {
        int row = wm * 32 + mi * 16 + (lane & 15);
        f32x4 p0 = *reinterpret_cast<const f32x4*>(&As[row * 64 + ((g0 ^ (row & 15)) << 2)]);
        f32x4 p1 = *reinterpret_cast<const f32x4*>(&As[row * 64 + (((g0 + 1) ^ (row & 15)) << 2)]);
        af[mi] = pack8(p0, p1);
      }
      const int gb = (kk >> 3) + (lane >> 4);
#pragma unroll
      for (int ni = 0; ni < 4; ++ni) {
        int row = wn * 64 + ni * 16 + (lane & 15);
        bfr[ni] = *reinterpret_cast<const bf16x8*>(&Bs[row * 64 + ((gb ^ (row & 7)) << 3)]);
      }
#pragma unroll
      for (int mi = 0; mi < 2; ++mi)
#pragma unroll
        for (int ni = 0; ni < 4; ++ni)
          acc[mi][ni] = __builtin_amdgcn_mfma_f32_16x16x32_bf16(af[mi], bfr[ni], acc[mi][ni], 0, 0, 0);
    }
    __syncthreads();
  }

  u16* outp = parts + (size_t)sk * ((size_t)NN * HH);
  const int r0 = (lane >> 4) << 2;
  const int coln = wn * 64 + (lane & 15);
#pragma unroll
  for (int mi = 0; mi < 2; ++mi)
#pragma unroll
    for (int ni = 0; ni < 4; ++ni)
#pragma unroll
      for (int r = 0; r < 4; ++r)
        outp[(size_t)(m0 + wm * 32 + mi * 16 + r0 + r) * HH + coln + ni * 16] = f2bf_rne(acc[mi][ni][r]);
}

// ---------------------------------------------------------------- gather: bf16 Q/A rows = sum of bf16 split-K parts
__global__ __launch_bounds__(256) void gather_qa(const u16* __restrict__ parts,
                                                 const int* __restrict__ q_idx,
                                                 const int* __restrict__ a_idx,
                                                 const int* __restrict__ rank,
                                                 u16* __restrict__ Qbf, u16* __restrict__ Abf) {
  const int rb = blockIdx.x;
  const bool isA = rb >= BB * LL;
  const int r = isA ? rb - BB * LL : rb;
  const int idx = (isA ? a_idx : q_idx)[r];
  const int cidx = rank[idx];
  const int tid = threadIdx.x;
  float s = 0.f;
#pragma unroll
  for (int p = 0; p < SPLITK; ++p)
    s += bf2f(parts[(size_t)p * ((size_t)NN * HH) + (size_t)cidx * HH + tid]);
  (isA ? Abf : Qbf)[(size_t)r * HH + tid] = f2bf_rne(s);
}

// ---------------------------------------------------------------- fused attention: score MFMA + row/col softmax
__global__ __launch_bounds__(512) void attn_fused(const u16* __restrict__ Qbf,
                                                  const u16* __restrict__ Abf,
                                                  u16* __restrict__ wqbf,
                                                  u16* __restrict__ watbf) {
  __shared__ __align__(16) char lraw[131072];
  u16* Qs = (u16*)lraw;
  u16* As = (u16*)(lraw + 65536);
  float* sc = (float*)lraw;
  const int b = blockIdx.x;
  const int tid = threadIdx.x;
  const int lane = tid & 63, wid = tid >> 6;
  const int wm = wid >> 2, wn = wid & 3;

  const u16* qsrc = Qbf + (size_t)b * (LL * HH);
  const u16* asrc = Abf + (size_t)b * (LL * HH);
#pragma unroll
  for (int i = 0; i < 8; ++i) {
    int gf = i * 512 + tid;
    int l = gf >> 5, g = gf & 31;
    int gp = g ^ (l & 7);
    *reinterpret_cast<bf16x8*>(&Qs[l * 256 + gp * 8]) = *reinterpret_cast<const bf16x8*>(qsrc + l * 256 + g * 8);
    *reinterpret_cast<bf16x8*>(&As[l * 256 + gp * 8]) = *reinterpret_cast<const bf16x8*>(asrc + l * 256 + g * 8);
  }
  __syncthreads();

  f32x4 acc[4][2];
  const f32x4 zf = {0.f, 0.f, 0.f, 0.f};
#pragma unroll
  for (int i = 0; i < 4; ++i)
#pragma unroll
    for (int j = 0; j < 2; ++j) acc[i][j] = zf;

#pragma unroll
  for (int ks = 0; ks < 8; ++ks) {
    bf16x8 af[4], bfr[2];
#pragma unroll
    for (int mi = 0; mi < 4; ++mi) {
      int row = wm * 64 + mi * 16 + (lane & 15);
      int g = ks * 4 + (lane >> 4);
      af[mi] = *reinterpret_cast<const bf16x8*>(&Qs[row * 256 + (g ^ (row & 7)) * 8]);
    }
#pragma unroll
    for (int ni = 0; ni < 2; ++ni) {
      int row = wn * 32 + ni * 16 + (lane & 15);
      int g = ks * 4 + (lane >> 4);
      bfr[ni] = *reinterpret_cast<const bf16x8*>(&As[row * 256 + (g ^ (row & 7)) * 8]);
    }
#pragma unroll
    for (int mi = 0; mi < 4; ++mi)
#pragma unroll
      for (int ni = 0; ni < 2; ++ni)
        acc[mi][ni] = __builtin_amdgcn_mfma_f32_16x16x32_bf16(af[mi], bfr[ni], acc[mi][ni], 0, 0, 0);
  }
  __syncthreads();

  const int r0 = (lane >> 4) << 2;
#pragma unroll
  for (int mi = 0; mi < 4; ++mi)
#pragma unroll
    for (int ni = 0; ni < 2; ++ni) {
      int m = wn * 32 + ni * 16 + (lane & 15);
#pragma unroll
      for (int r = 0; r < 4; ++r) {
        int l = wm * 64 + mi * 16 + r0 + r;
        sc[l * 132 + m] = acc[mi][ni][r];
      }
    }
  __syncthreads();

  {
    const int l = tid >> 2, j = tid & 3;
    const int base = l * 132 + j * 32;
    float mx = -3.4e38f;
#pragma unroll 8
    for (int c = 0; c < 32; ++c) mx = fmaxf(mx, sc[base + c]);
    mx = fmaxf(mx, __shfl_xor(mx, 1));
    mx = fmaxf(mx, __shfl_xor(mx, 2));
    float sum = 0.f;
#pragma unroll 8
    for (int c = 0; c < 32; ++c) sum += expf(sc[base + c] - mx);
    sum += __shfl_xor(sum, 1);
    sum += __shfl_xor(sum, 2);
    float inv = 1.f / sum;
    u16* o = wqbf + (size_t)b * (LL * LL) + l * 128 + j * 32;
#pragma unroll 8
    for (int c = 0; c < 32; ++c) o[c] = f2bf_rne(expf(sc[base + c] - mx) * inv);
  }
  {
    const int m = tid >> 2, j = tid & 3;
    float mx = -3.4e38f;
#pragma unroll 8
    for (int r = 0; r < 32; ++r) mx = fmaxf(mx, sc[(j * 32 + r) * 132 + m]);
    mx = fmaxf(mx, __shfl_xor(mx, 1));
    mx = fmaxf(mx, __shfl_xor(mx, 2));
    float sum = 0.f;
#pragma unroll 8
    for (int r = 0; r < 32; ++r) sum += expf(sc[(j * 32 + r) * 132 + m] - mx);
    sum += __shfl_xor(sum, 1);
    sum += __shfl_xor(sum, 2);
    float inv = 1.f / sum;
    u16* o = watbf + (size_t)b * (LL * LL) + m * 128 + j * 32;
#pragma unroll 8
    for (int r = 0; r < 32; ++r) o[r] = f2bf_rne(expf(sc[(j * 32 + r) * 132 + m] - mx) * inv);
  }
}

// ---------------------------------------------------------------- align via MFMA: E = w @ src; tq/ta -> Tbf
__global__ __launch_bounds__(512) void align_mfma(const u16* __restrict__ wqbf,
                                                  const u16* __restrict__ watbf,
                                                  const u16* __restrict__ Qbf,
                                                  const u16* __restrict__ Abf,
                                                  u16* __restrict__ Tbf) {
  __shared__ __align__(16) u16 wsh[128 * 128];
  __shared__ __align__(16) u16 srcT[256 * 140];
  const int bid = blockIdx.x;
  const int side = bid >> 5, b = bid & 31;
  const int tid = threadIdx.x;
  const int lane = tid & 63, wid = tid >> 6;
  const int wm = wid >> 2, wn = wid & 3;

  const u16* wsrc = (side ? watbf : wqbf) + (size_t)b * (LL * LL);
  const u16* ssrc = (side ? Qbf : Abf) + (size_t)b * (LL * HH);
  const u16* msrc = (side ? Abf : Qbf) + (size_t)b * (LL * HH);

#pragma unroll
  for (int i = 0; i < 4; ++i) {
    int gf = i * 512 + tid;
    int row = gf >> 4, g = gf & 15;
    int gp = g ^ (row & 7);
    *reinterpret_cast<bf16x8*>(&wsh[row * 128 + gp * 8]) = *reinterpret_cast<const bf16x8*>(wsrc + row * 128 + g * 8);
  }
#pragma unroll
  for (int i = 0; i < 8; ++i) {
    int gf = i * 512 + tid;
    int j = gf >> 5, g = gf & 31;
    bf16x8 v = *reinterpret_cast<const bf16x8*>(ssrc + j * 256 + g * 8);
#pragma unroll
    for (int e = 0; e < 8; ++e) srcT[(g * 8 + e) * 140 + j] = (u16)v[e];
  }
  __syncthreads();

  f32x4 acc[4][4];
  const f32x4 zf = {0.f, 0.f, 0.f, 0.f};
#pragma unroll
  for (int i = 0; i < 4; ++i)
#pragma unroll
    for (int j = 0; j < 4; ++j) acc[i][j] = zf;

#pragma unroll
  for (int ks = 0; ks < 4; ++ks) {
    bf16x8 af[4], bfr[4];
#pragma unroll
    for (int mi = 0; mi < 4; ++mi) {
      int row = wm * 64 + mi * 16 + (lane & 15);
      int g = ks * 4 + (lane >> 4);
      af[mi] = *reinterpret_cast<const bf16x8*>(&wsh[row * 128 + (g ^ (row & 7)) * 8]);
    }
#pragma unroll
    for (int ni = 0; ni < 4; ++ni) {
      int h = wn * 64 + ni * 16 + (lane & 15);
      int k = ks * 32 + ((lane >> 4) << 3);
      bfr[ni] = *reinterpret_cast<const bf16x8*>(&srcT[h * 140 + k]);
    }
#pragma unroll
    for (int mi = 0; mi < 4; ++mi)
#pragma unroll
      for (int ni = 0; ni < 4; ++ni)
        acc[mi][ni] = __builtin_amdgcn_mfma_f32_16x16x32_bf16(af[mi], bfr[ni], acc[mi][ni], 0, 0, 0);
  }

  u16* outp = Tbf + (size_t)(side * 4096 + b * 128) * 512;
  const int r0 = (lane >> 4) << 2;
#pragma unroll
  for (int mi = 0; mi < 4; ++mi)
#pragma unroll
    for (int ni = 0; ni < 4; ++ni) {
      int h = wn * 64 + ni * 16 + (lane & 15);
#pragma unroll
      for (int r = 0; r < 4; ++r) {
        int i2 = wm * 64 + mi * 16 + r0 + r;
        float mv = bf2f(msrc[(size_t)i2 * HH + h]);
        float e = acc[mi][ni][r];
        float d = mv - e;
        outp[(size_t)i2 * 512 + h] = f2bf_rne(d * d);
        outp[(size_t)i2 * 512 + 256 + h] = f2bf_rne(mv * e);
      }
    }
}

// ---------------------------------------------------------------- Wcat bf16 [1120][512]
__global__ __launch_bounds__(256) void prep_wcat(const float* __restrict__ w0,
                                                 const float* __restrict__ w1,
                                                 const float* __restrict__ w2,
                                                 const float* __restrict__ w3,
                                                 u16* __restrict__ Wcat) {
  const int kr = blockIdx.x;
  const int tid = threadIdx.x;
  u16* out = Wcat + (size_t)kr * 512;
  if (kr >= KK * 10) {
    out[tid] = 0;
    out[tid + 256] = 0;
    return;
  }
  const int k = kr / 10, s = kr % 10;
  const float* w;
  int r, fs;
  if (s < 1)      { w = w0; r = s;     fs = 1; }
  else if (s < 3) { w = w1; r = s - 1; fs = 2; }
  else if (s < 6) { w = w2; r = s - 3; fs = 3; }
  else            { w = w3; r = s - 6; fs = 4; }
  const float* src = w + ((size_t)k * fs + r) * 522 + 5;
  out[tid] = f2bf_rne(src[tid]);
  out[tid + 256] = f2bf_rne(src[tid + 256]);
}

// ---------------------------------------------------------------- fused conv GEMM + shift-sum/relu/maxpool -> re
// BM=128 (one (sel,b)), BN=160 (16 k-groups), K=512. grid 448 = 64 pairs x 7 ntiles.
// 8 waves 4Mx2N, acc[2][5]. Dt bf16 [128][162] OVERLAYS staging LDS (union 41.5 KB -> 2 blocks/CU).
__global__ __launch_bounds__(512, 4) void gemm_conv_red(const u16* __restrict__ Tbf,
                                                        const u16* __restrict__ Wcat,
                                                        const float* __restrict__ b0,
                                                        const float* __restrict__ b1,
                                                        const float* __restrict__ b2,
                                                        const float* __restrict__ b3,
                                                        float* __restrict__ re) {
  __shared__ __align__(16) char smem[41472];
  u16* As = (u16*)smem;              // [128][64] swizzled, 16 KB
  u16* Bs = (u16*)(smem + 16384);    // [160][64] swizzled, 20 KB
  u16* Dt = (u16*)smem;              // [128][162] bf16 epilogue overlay (41472 B)
  const int tid = threadIdx.x;
  const int lane = tid & 63, wid = tid >> 6;
  const int wm = wid >> 1, wn = wid & 1;
  const int bx = blockIdx.x;
  const int pair = bx / 7, nt = bx % 7;
  const int sel = pair >> 5, b = pair & 31;
  const int m0 = pair * 128;
  const int n0 = nt * 160;

  f32x4 acc[2][5];
  const f32x4 zf = {0.f, 0.f, 0.f, 0.f};
#pragma unroll
  for (int i = 0; i < 2; ++i)
#pragma unroll
    for (int j = 0; j < 5; ++j) acc[i][j] = zf;

  for (int s = 0; s < 8; ++s) {
    const int ks = s * 64;
#pragma unroll
    for (int j = 0; j < 2; ++j) {
      int t = wid * 2 + j;
      int rowA = t * 8 + (lane >> 3);
      int kA = ((lane & 7) ^ (rowA & 7)) << 3;
      gld16(Tbf + (size_t)(m0 + rowA) * 512 + ks + kA, (void*)&As[t * 512]);
    }
    for (int t = wid; t < 20; t += 8) {
      int rowB = t * 8 + (lane >> 3);
      int kB = ((lane & 7) ^ (rowB & 7)) << 3;
      gld16(Wcat + (size_t)(n0 + rowB) * 512 + ks + kB, (void*)&Bs[t * 512]);
    }
    __syncthreads();
#pragma unroll
    for (int kk = 0; kk < 64; kk += 32) {
      const int k8 = (kk >> 3) + (lane >> 4);
      bf16x8 af[2], bfr[5];
#pragma unroll
      for (int mi = 0; mi < 2; ++mi) {
        int row = wm * 32 + mi * 16 + (lane & 15);
        af[mi] = *reinterpret_cast<const bf16x8*>(&As[row * 64 + ((k8 ^ (row & 7)) << 3)]);
      }
#pragma unroll
      for (int ni = 0; ni < 5; ++ni) {
        int row = wn * 80 + ni * 16 + (lane & 15);
        bfr[ni] = *reinterpret_cast<const bf16x8*>(&Bs[row * 64 + ((k8 ^ (row & 7)) << 3)]);
      }
#pragma unroll
      for (int mi = 0; mi < 2; ++mi)
#pragma unroll
        for (int ni = 0; ni < 5; ++ni)
          acc[mi][ni] = __builtin_amdgcn_mfma_f32_16x16x32_bf16(af[mi], bfr[ni], acc[mi][ni], 0, 0, 0);
    }
    __syncthreads();
  }

  // acc -> Dt (bf16), overlaying dead staging LDS
  const int r0 = (lane >> 4) << 2;
#pragma unroll
  for (int mi = 0; mi < 2; ++mi)
#pragma unroll
    for (int ni = 0; ni < 5; ++ni) {
      int col = wn * 80 + ni * 16 + (lane & 15);
#pragma unroll
      for (int r = 0; r < 4; ++r)
        Dt[(wm * 32 + mi * 16 + r0 + r) * 162 + col] = f2bf_rne(acc[mi][ni][r]);
    }
  __syncthreads();

  // epilogue: 64 outputs (16 k-groups x 4 filter sizes), 8 per wave
  const int offt[4] = {0, 1, 3, 6};
  const int fst[4] = {1, 2, 3, 4};
#pragma unroll
  for (int oi = 0; oi < 8; ++oi) {
    const int o = wid * 8 + oi;
    const int kl = o >> 2, f = o & 3;
    const int kglob = nt * 16 + kl;
    if (kglob >= KK) continue;
    const int fs = fst[f], off = offt[f];
    const float bias = (f == 0 ? b0 : f == 1 ? b1 : f == 2 ? b2 : b3)[kglob];
    const int col = kl * 10 + off;
    const int outh = 139 - fs;
    float best = 0.f;
    for (int i = lane; i < outh; i += 64) {
      float s = bias;
#pragma unroll 4
      for (int r = 0; r < 4; ++r) {
        if (r < fs) {
          int j = i + r - 5;
          if (j >= 0 && j < LL) s += bf2f(Dt[j * 162 + col + r]);
        }
      }
      best = fmaxf(best, s);
    }
    best = fmaxf(best, 0.f);
#pragma unroll
    for (int d = 32; d; d >>= 1) best = fmaxf(best, __shfl_xor(best, d));
    if (lane == 0) re[(size_t)b * 800 + sel * 400 + f * 100 + kglob] = best;
  }
}

// ---------------------------------------------------------------- dense + log_softmax -> out[32][2]
__global__ __launch_bounds__(64) void dense_logsm(const float* __restrict__ re,
                                                  const float* __restrict__ dw,
                                                  const float* __restrict__ db,
                                                  float* __restrict__ out) {
  const int b = blockIdx.x;
  const int lane = threadIdx.x;
  const float* r = re + (size_t)b * 800;
  float a0 = 0.f, a1 = 0.f;
  for (int j = lane; j < 800; j += 64) {
    float rv = r[j];
    a0 += rv * dw[j * 2];
    a1 += rv * dw[j * 2 + 1];
  }
#pragma unroll
  for (int d = 32; d; d >>= 1) {
    a0 += __shfl_xor(a0, d);
    a1 += __shfl_xor(a1, d);
  }
  if (lane == 0) {
    a0 += db[0];
    a1 += db[1];
    float mx = fmaxf(a0, a1);
    float lse = mx + logf(expf(a0 - mx) + expf(a1 - mx));
    out[b * 2] = a0 - lse;
    out[b * 2 + 1] = a1 - lse;
  }
}

// ---------------------------------------------------------------- workspace layout (bytes)
static const size_t OFF_PARTS = 0;                         // bf16: 8 * 8192*256 u16 = 33.5 MB (region 67MB)
static const size_t OFF_QBF   = 67108864;
static const size_t OFF_ABF   = OFF_QBF + 2097152;
static const size_t OFF_WQB   = OFF_ABF + 2097152;
static const size_t OFF_WAB   = OFF_WQB + 1048576;
static const size_t OFF_RE    = OFF_WAB + 1048576;
static const size_t OFF_TBF   = OFF_RE + 102400;
static const size_t OFF_WCAT  = OFF_TBF + 8388608;         // bf16 [1120][512] = 1,146,880
static const size_t OFF_EMBT  = OFF_WCAT + 1146880;
static const size_t OFF_RANK  = OFF_EMBT + 4194304;
static const size_t OFF_ROWS  = OFF_RANK + 32768;
static const size_t OFF_MUNIQ = OFF_ROWS + 33280;

extern "C" void kernel_launch(void* const* d_in, const int* in_sizes, int n_in,
                              void* d_out, int out_size, void* d_ws, size_t ws_size,
                              hipStream_t stream) {
  (void)in_sizes; (void)n_in; (void)out_size; (void)ws_size;
  const float* adj  = (const float*)d_in[0];
  const float* emb  = (const float*)d_in[1];
  const int* q_idx  = (const int*)d_in[2];
  const int* a_idx  = (const int*)d_in[3];
  const float* cw0 = (const float*)d_in[4];
  const float* cb0 = (const float*)d_in[5];
  const float* cw1 = (const float*)d_in[6];
  const float* cb1 = (const float*)d_in[7];
  const float* cw2 = (const float*)d_in[8];
  const float* cb2 = (const float*)d_in[9];
  const float* cw3 = (const float*)d_in[10];
  const float* cb3 = (const float*)d_in[11];
  const float* dw = (const float*)d_in[12];
  const float* db = (const float*)d_in[13];
  float* out = (float*)d_out;

  char* ws = (char*)d_ws;
  u16* parts   = (u16*)(ws + OFF_PARTS);
  u16* Qbf     = (u16*)(ws + OFF_QBF);
  u16* Abf     = (u16*)(ws + OFF_ABF);
  u16* wqbf    = (u16*)(ws + OFF_WQB);
  u16* watbf   = (u16*)(ws + OFF_WAB);
  float* re    = (float*)(ws + OFF_RE);
  u16* Tbf     = (u16*)(ws + OFF_TBF);
  u16* Wcat    = (u16*)(ws + OFF_WCAT);
  u16* embT    = (u16*)(ws + OFF_EMBT);
  int* rank    = (int*)(ws + OFF_RANK);
  int* rows    = (int*)(ws + OFF_ROWS);
  int* muniq   = (int*)(ws + OFF_MUNIQ);

  convert_embT<<<dim3(128, 4), 256, 0, stream>>>(emb, embT);
  dedup_rows<<<1, 1024, 0, stream>>>(q_idx, a_idx, rank, rows, muniq);
  prep_wcat<<<WCATR, 256, 0, stream>>>(cw0, cw1, cw2, cw3, Wcat);
  gemm_layer1c<<<128 * SPLITK, 512, 0, stream>>>(adj, embT, rows, muniq, parts);
  gather_qa<<<2 * BB * LL, 256, 0, stream>>>(parts, q_idx, a_idx, rank, Qbf, Abf);
  attn_fused<<<BB, 512, 0, stream>>>(Qbf, Abf, wqbf, watbf);
  align_mfma<<<64, 512, 0, stream>>>(wqbf, watbf, Qbf, Abf, Tbf);
  gemm_conv_red<<<448, 512, 0, stream>>>(Tbf, Wcat, cb0, cb1, cb2, cb3, re);
  dense_logsm<<<BB, 64, 0, stream>>>(re, dw, db, out);
}